// Round 4
// baseline (1654.078 us; speedup 1.0000x reference)
//
#include <hip/hip_runtime.h>
#include <hip/hip_bf16.h>

typedef __bf16 bfx8 __attribute__((ext_vector_type(8)));
typedef __bf16 bfx4 __attribute__((ext_vector_type(4)));
typedef float  f32x4 __attribute__((ext_vector_type(4)));

#define MFMA16(a,b,c) __builtin_amdgcn_mfma_f32_16x16x32_bf16((a),(b),(c),0,0,0)

__device__ __forceinline__ float clampf(float v, float lim) {
  return fminf(fmaxf(v, -lim), lim);   // NaN-laundering insurance; invisible for legit values
}

// B=4, SM=1024, SI=4096, D=256, H=8, FF=1024
// All external I/O is FLOAT32 (reference is jnp.float32 end-to-end).
// Internal: bf16 operands + f32 accumulation.

// ---------------- weight transpose + downcast: dst_bf16[c*R+r] = src_f32[r*C+c] ----------------
__global__ void transpose_k(const float* __restrict__ src, __bf16* __restrict__ dst,
                            int R, int C) {
  long base = (long)blockIdx.y * R * C;
  int i = blockIdx.x * 256 + threadIdx.x;
  if (i < R * C) {
    int r = i / C, c = i % C;
    dst[base + (long)c * R + r] = (__bf16)src[base + i];
  }
}

// ---------------- GEMM: C[M,N] = act(X[M,K] @ Wt[N,K]^T + bias[N]) ----------------
// X comes from either a bf16 workspace buffer (Xb) or an f32 input (Xfb) — one is null.
__global__ __launch_bounds__(256)
void gemm_bt(const __bf16* __restrict__ Xb, const float* __restrict__ Xfb,
             const __bf16* __restrict__ Wtb,
             const float* __restrict__ biasb, __bf16* __restrict__ Cb,
             int M, int N, int K, int act,
             long xz, long wz, long bz, long cz) {
  const __bf16* X  = Xb  ? Xb  + (long)blockIdx.z * xz : nullptr;
  const float*  Xf = Xfb ? Xfb + (long)blockIdx.z * xz : nullptr;
  const __bf16* Wt   = Wtb   + (long)blockIdx.z * wz;
  const float*  bias = biasb + (long)blockIdx.z * bz;
  __bf16*       C    = Cb    + (long)blockIdx.z * cz;

  __shared__ __bf16 xs[128][72];     // +8 pad
  __shared__ __bf16 wsm[128][72];

  const int tid  = threadIdx.x;
  const int lane = tid & 63;
  const int w    = tid >> 6;
  const int l15  = lane & 15;
  const int quad = lane >> 4;
  const int wm   = (w >> 1) * 64;
  const int wn   = (w & 1) * 64;
  const int m0   = blockIdx.x * 128;
  const int n0   = blockIdx.y * 128;

  f32x4 acc[4][4];
#pragma unroll
  for (int i = 0; i < 4; i++)
#pragma unroll
    for (int j = 0; j < 4; j++) acc[i][j] = (f32x4){0.f, 0.f, 0.f, 0.f};

  for (int kk = 0; kk < K; kk += 64) {
    __syncthreads();
#pragma unroll
    for (int rep = 0; rep < 4; rep++) {
      int idx = rep * 256 + tid;
      int row = idx >> 3;             // 0..127
      int g   = idx & 7;              // 8 bf16 each
      if (Xf) {
        const float* p = Xf + (long)(m0 + row) * K + kk + g * 8;
        f32x4 a0 = *(const f32x4*)p;
        f32x4 a1 = *(const f32x4*)(p + 4);
        bfx8 v;
#pragma unroll
        for (int j = 0; j < 4; j++) { v[j] = (__bf16)a0[j]; v[4 + j] = (__bf16)a1[j]; }
        *(bfx8*)&xs[row][g * 8] = v;
      } else {
        *(bfx8*)&xs[row][g * 8] = *(const bfx8*)(X + (long)(m0 + row) * K + kk + g * 8);
      }
      *(bfx8*)&wsm[row][g * 8] = *(const bfx8*)(Wt + (long)(n0 + row) * K + kk + g * 8);
    }
    __syncthreads();
#pragma unroll
    for (int ks = 0; ks < 2; ks++) {
      bfx8 af[4], bf_[4];
#pragma unroll
      for (int i = 0; i < 4; i++) af[i]  = *(const bfx8*)&xs[wm + 16 * i + l15][ks * 32 + quad * 8];
#pragma unroll
      for (int j = 0; j < 4; j++) bf_[j] = *(const bfx8*)&wsm[wn + 16 * j + l15][ks * 32 + quad * 8];
#pragma unroll
      for (int i = 0; i < 4; i++)
#pragma unroll
        for (int j = 0; j < 4; j++) acc[i][j] = MFMA16(af[i], bf_[j], acc[i][j]);
    }
  }

#pragma unroll
  for (int j = 0; j < 4; j++) {
    int n = n0 + wn + 16 * j + l15;
    float bv = bias[n];
#pragma unroll
    for (int i = 0; i < 4; i++) {
#pragma unroll
      for (int r = 0; r < 4; r++) {
        int m = m0 + wm + 16 * i + quad * 4 + r;   // C/D: row = quad*4+reg
        float v = clampf(acc[i][j][r] + bv, 60000.f);
        if (act == 1) v = fmaxf(v, 0.f);
        C[(long)m * N + n] = (__bf16)v;
      }
    }
  }
}

// ---------------- fused multi-query attention ----------------
// grid (SM/64, B, H), block 256 (4 waves). Wave w owns Q rows 16w..16w+15.
__global__ __launch_bounds__(256)
void attn_kernel(const __bf16* __restrict__ qb,   // [H][B*SM][256]
                 const __bf16* __restrict__ ik,   // [B*SI][256]
                 const __bf16* __restrict__ iv,   // [B*SI][256]
                 const __bf16* __restrict__ mk,   // [B*SM][256]
                 const __bf16* __restrict__ mv,   // [B*SM][256]
                 __bf16* __restrict__ concat) {   // [B*SM][2048]
  __shared__ __bf16 lk[32][264];
  __shared__ __bf16 lvt[256][40];
  __shared__ __bf16 lp[64][40];

  const int tid  = threadIdx.x;
  const int lane = tid & 63;
  const int w    = tid >> 6;
  const int l15  = lane & 15;
  const int quad = lane >> 4;

  const int m0 = blockIdx.x * 64;
  const int b  = blockIdx.y;
  const int h  = blockIdx.z;

  const long qbase  = ((long)h * 4096 + b * 1024 + m0) * 256;
  const long kvbase = (long)b * 4096 * 256;
  const long mbase  = ((long)b * 1024 + m0) * 256;

  bfx8 qf[8];
  {
    const __bf16* qrow = qb + qbase + (long)(16 * w + l15) * 256 + quad * 8;
#pragma unroll
    for (int ks = 0; ks < 8; ks++) qf[ks] = *(const bfx8*)(qrow + ks * 32);
  }

  // self score for row 16w+l15, kept in registers
  float ps_l;
  {
    const __bf16* krow = mk + mbase + (long)(16 * w + l15) * 256 + quad * 8;
    float s = 0.f;
#pragma unroll
    for (int ks = 0; ks < 8; ks++) {
      bfx8 kv = *(const bfx8*)(krow + ks * 32);
#pragma unroll
      for (int j = 0; j < 8; j++) s += (float)qf[ks][j] * (float)kv[j];
    }
    s += __shfl_xor(s, 16);
    s += __shfl_xor(s, 32);
    ps_l = __expf(clampf(s * 0.0625f, 30.f));
  }

  f32x4 acc[16];
#pragma unroll
  for (int i = 0; i < 16; i++) acc[i] = (f32x4){0.f, 0.f, 0.f, 0.f};
  float den[4] = {0.f, 0.f, 0.f, 0.f};

  for (int sc = 0; sc < 128; sc++) {
    __syncthreads();
#pragma unroll
    for (int rep = 0; rep < 4; rep++) {
      int idx = rep * 256 + tid;
      int s   = idx >> 5;
      int g   = idx & 31;
      long grow = kvbase + (long)(sc * 32 + s) * 256 + g * 8;
      *(bfx8*)&lk[s][g * 8] = *(const bfx8*)(ik + grow);
      bfx8 vv = *(const bfx8*)(iv + grow);
#pragma unroll
      for (int j = 0; j < 8; j++) lvt[g * 8 + j][s] = vv[j];
    }
    __syncthreads();

    // S = Q K^T
    f32x4 sacc[2];
    sacc[0] = (f32x4){0.f, 0.f, 0.f, 0.f};
    sacc[1] = (f32x4){0.f, 0.f, 0.f, 0.f};
#pragma unroll
    for (int ks = 0; ks < 8; ks++) {
      bfx8 b0 = *(const bfx8*)&lk[l15][ks * 32 + quad * 8];
      bfx8 b1 = *(const bfx8*)&lk[16 + l15][ks * 32 + quad * 8];
      sacc[0] = MFMA16(qf[ks], b0, sacc[0]);
      sacc[1] = MFMA16(qf[ks], b1, sacc[1]);
    }

    // P = exp(S/16)
#pragma unroll
    for (int ct = 0; ct < 2; ct++) {
      float rs[4];
#pragma unroll
      for (int r = 0; r < 4; r++) {
        float p = __expf(clampf(sacc[ct][r] * 0.0625f, 30.f));
        rs[r] = p;
        lp[16 * w + quad * 4 + r][ct * 16 + l15] = (__bf16)p;
      }
#pragma unroll
      for (int r = 0; r < 4; r++) {
        float v = rs[r];
        v += __shfl_xor(v, 1);
        v += __shfl_xor(v, 2);
        v += __shfl_xor(v, 4);
        v += __shfl_xor(v, 8);
        den[r] += v;
      }
    }

    __syncthreads();

    // O += P V
    bfx8 pf = *(const bfx8*)&lp[16 * w + l15][quad * 8];
#pragma unroll
    for (int dt = 0; dt < 16; dt++) {
      bfx8 vf = *(const bfx8*)&lvt[dt * 16 + l15][quad * 8];
      acc[dt] = MFMA16(pf, vf, acc[dt]);
    }
  }

  // epilogue
#pragma unroll
  for (int r = 0; r < 4; r++) {
    int ml = 16 * w + quad * 4 + r;
    float ps = __shfl(ps_l, quad * 4 + r);
    float dinv = 1.f / (den[r] + ps);
    const __bf16* mvrow = mv + mbase + (long)ml * 256;
    __bf16* crow = concat + ((long)(b * 1024 + m0 + ml)) * 2048 + h * 256;
#pragma unroll
    for (int dt = 0; dt < 16; dt++) {
      int d = dt * 16 + l15;
      float o = clampf((acc[dt][r] + ps * (float)mvrow[d]) * dinv, 60000.f);
      crow[d] = (__bf16)o;
    }
  }
}

// ---------------- LayerNorm with residual: out = LN(a + res)*g + b ----------------
// a: bf16, res: f32. Writes bf16 (outb, if non-null) and f32 (outf, if non-null).
__global__ __launch_bounds__(256)
void ln_kernel(const __bf16* __restrict__ a, const float* __restrict__ res,
               const float* __restrict__ g, const float* __restrict__ beta,
               __bf16* __restrict__ outb, float* __restrict__ outf) {
  int row  = blockIdx.x * 4 + (threadIdx.x >> 6);
  int lane = threadIdx.x & 63;
  const __bf16* ar = a   + (long)row * 256;
  const float*  rr = res + (long)row * 256;
  bfx4  av = *(const bfx4*)(ar + lane * 4);
  f32x4 rv = *(const f32x4*)(rr + lane * 4);
  float v[4], s1 = 0.f, s2 = 0.f;
#pragma unroll
  for (int i = 0; i < 4; i++) {
    v[i] = clampf((float)av[i] + rv[i], 30000.f);
    s1 += v[i];
    s2 += v[i] * v[i];
  }
#pragma unroll
  for (int off = 32; off >= 1; off >>= 1) {
    s1 += __shfl_xor(s1, off);
    s2 += __shfl_xor(s2, off);
  }
  float mean = s1 * (1.f / 256.f);
  float var  = fmaxf(s2 * (1.f / 256.f) - mean * mean, 0.f);
  float rstd = rsqrtf(var + 1e-6f);
#pragma unroll
  for (int i = 0; i < 4; i++) {
    int c = lane * 4 + i;
    float o = (v[i] - mean) * rstd * g[c] + beta[c];
    if (outb) outb[(long)row * 256 + c] = (__bf16)o;
    if (outf) outf[(long)row * 256 + c] = o;
  }
}

// ---------------- elementwise multiply (bf16 in/out) ----------------
__global__ void mul_kernel(const __bf16* __restrict__ a, const __bf16* __restrict__ b,
                           __bf16* __restrict__ o, int n8) {
  int i = blockIdx.x * 256 + threadIdx.x;
  if (i < n8) {
    bfx8 x = *(const bfx8*)(a + (long)i * 8);
    bfx8 y = *(const bfx8*)(b + (long)i * 8);
    bfx8 z;
#pragma unroll
    for (int j = 0; j < 8; j++) z[j] = (__bf16)clampf((float)x[j] * (float)y[j], 60000.f);
    *(bfx8*)(o + (long)i * 8) = z;
  }
}

extern "C" void kernel_launch(void* const* d_in, const int* in_sizes, int n_in,
                              void* d_out, int out_size, void* d_ws, size_t ws_size,
                              hipStream_t stream) {
  // ALL inputs are float32 (reference dtype). Output is float32.
  const float* state  = (const float*)d_in[0];   // [4,1024,256]
  const float* input  = (const float*)d_in[1];   // [4,4096,256]
  const float* Wk     = (const float*)d_in[2];
  const float* bk     = (const float*)d_in[3];
  const float* Wv     = (const float*)d_in[4];
  const float* bv     = (const float*)d_in[5];
  const float* Wq     = (const float*)d_in[6];   // [8,256,256]
  const float* bq     = (const float*)d_in[7];   // [8,256]
  const float* Wo     = (const float*)d_in[8];   // [2048,256]
  const float* bo     = (const float*)d_in[9];
  const float* ln1g   = (const float*)d_in[10];
  const float* ln1b   = (const float*)d_in[11];
  const float* W_in   = (const float*)d_in[12];  // [256,1024]
  const float* b_in   = (const float*)d_in[13];
  const float* Wg_nl  = (const float*)d_in[14];  // [1024,1024]
  const float* bg_nl  = (const float*)d_in[15];
  const float* Wg_l   = (const float*)d_in[16];
  const float* bg_l   = (const float*)d_in[17];
  const float* Wg_o   = (const float*)d_in[18];  // [1024,256]
  const float* bg_o   = (const float*)d_in[19];
  const float* ln2g   = (const float*)d_in[20];
  const float* ln2b   = (const float*)d_in[21];
  float* out = (float*)d_out;

  const size_t needed_elems = 28442624;          // 56.9 MB as bf16 (proven to fit: r3 ran)
  if (ws_size < needed_elems * sizeof(__bf16)) return;

  __bf16* ws = (__bf16*)d_ws;
  size_t off = 0;
  auto alloc = [&](size_t n) { __bf16* p = ws + off; off += n; return p; };
  __bf16* Wkt    = alloc(65536);
  __bf16* Wvt    = alloc(65536);
  __bf16* Wqt    = alloc(524288);
  __bf16* Wot    = alloc(524288);
  __bf16* ik     = alloc(4194304);   // [4*4096,256]
  __bf16* iv     = alloc(4194304);
  __bf16* mk     = alloc(1048576);   // [4*1024,256]
  __bf16* mv     = alloc(1048576);
  __bf16* qbuf   = alloc(8388608);   // [8][4096][256]
  __bf16* concat = alloc(8388608);   // [4096][2048]
  // FFN-phase aliases over dead attention buffers
  __bf16* attn_o = mk;               // [4096,256]
  __bf16* x      = mv;               // [4096,256] bf16 (GEMM operand)
  __bf16* hbuf   = ik;               // [4096,1024]
  __bf16* t1     = iv;               // [4096,1024]
  __bf16* t2     = qbuf;             // [4096,1024]
  __bf16* gbuf   = qbuf + 4194304;   // [4096,1024]
  __bf16* W_int  = concat;           // 262144
  __bf16* Wg_nlt = concat + 262144;  // 1048576
  __bf16* Wg_lt  = concat + 1310720; // 1048576
  __bf16* Wg_ot  = concat + 2359296; // 262144
  __bf16* ff     = concat + 2621440; // 1048576
  float*  xf     = (float*)(concat + 3670016); // [4096,256] f32 residual (4 MB; concat has room)

  dim3 blk(256);

  transpose_k<<<dim3(256, 1), blk, 0, stream>>>(Wk, Wkt, 256, 256);
  transpose_k<<<dim3(256, 1), blk, 0, stream>>>(Wv, Wvt, 256, 256);
  transpose_k<<<dim3(256, 8), blk, 0, stream>>>(Wq, Wqt, 256, 256);
  transpose_k<<<dim3(2048, 1), blk, 0, stream>>>(Wo, Wot, 2048, 256);

  // projections (X = f32 inputs)
  gemm_bt<<<dim3(128, 2), blk, 0, stream>>>(nullptr, input, Wkt, bk, ik, 16384, 256, 256, 0, 0, 0, 0, 0);
  gemm_bt<<<dim3(128, 2), blk, 0, stream>>>(nullptr, input, Wvt, bv, iv, 16384, 256, 256, 0, 0, 0, 0, 0);
  gemm_bt<<<dim3(32, 2), blk, 0, stream>>>(nullptr, state, Wkt, bk, mk, 4096, 256, 256, 0, 0, 0, 0, 0);
  gemm_bt<<<dim3(32, 2), blk, 0, stream>>>(nullptr, state, Wvt, bv, mv, 4096, 256, 256, 0, 0, 0, 0, 0);
  gemm_bt<<<dim3(32, 2, 8), blk, 0, stream>>>(nullptr, state, Wqt, bq, qbuf, 4096, 256, 256, 0,
                                              0, 65536, 256, 1048576);

  attn_kernel<<<dim3(16, 4, 8), blk, 0, stream>>>(qbuf, ik, iv, mk, mv, concat);

  gemm_bt<<<dim3(32, 2), blk, 0, stream>>>(concat, nullptr, Wot, bo, attn_o, 4096, 256, 2048, 0, 0, 0, 0, 0);
  ln_kernel<<<dim3(1024), blk, 0, stream>>>(attn_o, state, ln1g, ln1b, x, xf);

  // FFN weight transposes (concat region dead; xf sits past them)
  transpose_k<<<dim3(1024, 1), blk, 0, stream>>>(W_in, W_int, 256, 1024);
  transpose_k<<<dim3(4096, 1), blk, 0, stream>>>(Wg_nl, Wg_nlt, 1024, 1024);
  transpose_k<<<dim3(4096, 1), blk, 0, stream>>>(Wg_l, Wg_lt, 1024, 1024);
  transpose_k<<<dim3(1024, 1), blk, 0, stream>>>(Wg_o, Wg_ot, 1024, 256);

  gemm_bt<<<dim3(32, 8), blk, 0, stream>>>(x, nullptr, W_int, b_in, hbuf, 4096, 1024, 256, 1, 0, 0, 0, 0);
  gemm_bt<<<dim3(32, 8), blk, 0, stream>>>(hbuf, nullptr, Wg_nlt, bg_nl, t1, 4096, 1024, 1024, 1, 0, 0, 0, 0);
  gemm_bt<<<dim3(32, 8), blk, 0, stream>>>(hbuf, nullptr, Wg_lt, bg_l, t2, 4096, 1024, 1024, 0, 0, 0, 0, 0);
  mul_kernel<<<dim3(2048), blk, 0, stream>>>(t1, t2, gbuf, 524288);
  gemm_bt<<<dim3(32, 2), blk, 0, stream>>>(gbuf, nullptr, Wg_ot, bg_o, ff, 4096, 256, 1024, 0, 0, 0, 0, 0);
  ln_kernel<<<dim3(1024), blk, 0, stream>>>(ff, xf, ln2g, ln2b, nullptr, out);
}

// Round 5
// 826.135 us; speedup vs baseline: 2.0022x; 2.0022x over previous
//
#include <hip/hip_runtime.h>
#include <hip/hip_bf16.h>

typedef __bf16 bfx8 __attribute__((ext_vector_type(8)));
typedef __bf16 bfx4 __attribute__((ext_vector_type(4)));
typedef float  f32x4 __attribute__((ext_vector_type(4)));

#define MFMA16(a,b,c) __builtin_amdgcn_mfma_f32_16x16x32_bf16((a),(b),(c),0,0,0)

__device__ __forceinline__ float clampf(float v, float lim) {
  return fminf(fmaxf(v, -lim), lim);
}

// B=4, SM=1024, SI=4096, D=256, H=8, FF=1024
// External I/O: float32. Internal: bf16 operands + f32 accumulation.

// ---------------- weight transpose + downcast: dst_bf16[c*R+r] = src_f32[r*C+c] ----------------
__global__ void transpose_k(const float* __restrict__ src, __bf16* __restrict__ dst,
                            int R, int C) {
  long base = (long)blockIdx.y * R * C;
  int i = blockIdx.x * 256 + threadIdx.x;
  if (i < R * C) {
    int r = i / C, c = i % C;
    dst[base + (long)c * R + r] = (__bf16)src[base + i];
  }
}

// ---------------- GEMM: C[M,N] = act(X[M,K] @ Wt[N,K]^T + bias[N]) ----------------
// cmode 0: row-major C.  cmode 2: V chunk-transposed store for attention:
//   C_idx = ((b*128 + (m%4096)/32)*256 + n)*32 + m%32   (b = m/4096)
__global__ __launch_bounds__(256)
void gemm_bt(const __bf16* __restrict__ Xb, const float* __restrict__ Xfb,
             const __bf16* __restrict__ Wtb,
             const float* __restrict__ biasb, __bf16* __restrict__ Cb,
             int M, int N, int K, int act, int cmode,
             long xz, long wz, long bz, long cz) {
  const __bf16* X  = Xb  ? Xb  + (long)blockIdx.z * xz : nullptr;
  const float*  Xf = Xfb ? Xfb + (long)blockIdx.z * xz : nullptr;
  const __bf16* Wt   = Wtb   + (long)blockIdx.z * wz;
  const float*  bias = biasb + (long)blockIdx.z * bz;
  __bf16*       C    = Cb    + (long)blockIdx.z * cz;

  __shared__ __bf16 xs[128][72];
  __shared__ __bf16 wsm[128][72];

  const int tid  = threadIdx.x;
  const int lane = tid & 63;
  const int w    = tid >> 6;
  const int l15  = lane & 15;
  const int quad = lane >> 4;
  const int wm   = (w >> 1) * 64;
  const int wn   = (w & 1) * 64;
  const int m0   = blockIdx.x * 128;
  const int n0   = blockIdx.y * 128;

  f32x4 acc[4][4];
#pragma unroll
  for (int i = 0; i < 4; i++)
#pragma unroll
    for (int j = 0; j < 4; j++) acc[i][j] = (f32x4){0.f, 0.f, 0.f, 0.f};

  for (int kk = 0; kk < K; kk += 64) {
    __syncthreads();
#pragma unroll
    for (int rep = 0; rep < 4; rep++) {
      int idx = rep * 256 + tid;
      int row = idx >> 3;
      int g   = idx & 7;
      if (Xf) {
        const float* p = Xf + (long)(m0 + row) * K + kk + g * 8;
        f32x4 a0 = *(const f32x4*)p;
        f32x4 a1 = *(const f32x4*)(p + 4);
        bfx8 v;
#pragma unroll
        for (int j = 0; j < 4; j++) { v[j] = (__bf16)a0[j]; v[4 + j] = (__bf16)a1[j]; }
        *(bfx8*)&xs[row][g * 8] = v;
      } else {
        *(bfx8*)&xs[row][g * 8] = *(const bfx8*)(X + (long)(m0 + row) * K + kk + g * 8);
      }
      *(bfx8*)&wsm[row][g * 8] = *(const bfx8*)(Wt + (long)(n0 + row) * K + kk + g * 8);
    }
    __syncthreads();
#pragma unroll
    for (int ks = 0; ks < 2; ks++) {
      bfx8 af[4], bf_[4];
#pragma unroll
      for (int i = 0; i < 4; i++) af[i]  = *(const bfx8*)&xs[wm + 16 * i + l15][ks * 32 + quad * 8];
#pragma unroll
      for (int j = 0; j < 4; j++) bf_[j] = *(const bfx8*)&wsm[wn + 16 * j + l15][ks * 32 + quad * 8];
#pragma unroll
      for (int i = 0; i < 4; i++)
#pragma unroll
        for (int j = 0; j < 4; j++) acc[i][j] = MFMA16(af[i], bf_[j], acc[i][j]);
    }
  }

#pragma unroll
  for (int j = 0; j < 4; j++) {
    int n = n0 + wn + 16 * j + l15;
    float bv = bias[n];
#pragma unroll
    for (int i = 0; i < 4; i++) {
#pragma unroll
      for (int r = 0; r < 4; r++) {
        int m = m0 + wm + 16 * i + quad * 4 + r;
        float v = clampf(acc[i][j][r] + bv, 60000.f);
        if (act == 1) v = fmaxf(v, 0.f);
        if (cmode == 2) {
          int b = m >> 12, si = m & 4095;
          C[((long)(b * 128 + (si >> 5)) * 256 + n) * 32 + (si & 31)] = (__bf16)v;
        } else {
          C[(long)m * N + n] = (__bf16)v;
        }
      }
    }
  }
}

// ---------------- fused multi-query attention ----------------
// grid (SM/64, B, H), block 256 (4 waves). Wave w owns Q rows 16w..16w+15.
// V arrives pre-transposed per 32-key chunk: ivT[b][sc][d][s] -> linear LDS staging.
__global__ __launch_bounds__(256)
void attn_kernel(const __bf16* __restrict__ qb,   // [H][B*SM][256]
                 const __bf16* __restrict__ ik,   // [B*SI][256]
                 const __bf16* __restrict__ ivT,  // [B][128][256][32]
                 const __bf16* __restrict__ mk,   // [B*SM][256]
                 const __bf16* __restrict__ mv,   // [B*SM][256]
                 __bf16* __restrict__ concat) {   // [B*SM][2048]
  __shared__ __bf16 lk[32][264];    // K chunk [s][d], +8 pad (even bank spread)
  __shared__ __bf16 lvt[8192];      // V^T chunk flat [d][s32] (linear, conflict-free)
  __shared__ __bf16 lp[64][40];     // P tile [m][s]

  const int tid  = threadIdx.x;
  const int lane = tid & 63;
  const int w    = tid >> 6;
  const int l15  = lane & 15;
  const int quad = lane >> 4;

  const int m0 = blockIdx.x * 64;
  const int b  = blockIdx.y;
  const int h  = blockIdx.z;

  const long qbase  = ((long)h * 4096 + b * 1024 + m0) * 256;
  const long kvbase = (long)b * 4096 * 256;
  const long vtbase = (long)b * 128 * 8192;
  const long mbase  = ((long)b * 1024 + m0) * 256;

  bfx8 qf[8];
  {
    const __bf16* qrow = qb + qbase + (long)(16 * w + l15) * 256 + quad * 8;
#pragma unroll
    for (int ks = 0; ks < 8; ks++) qf[ks] = *(const bfx8*)(qrow + ks * 32);
  }

  // self score for row 16w+l15 (registers only)
  float ps_l;
  {
    const __bf16* krow = mk + mbase + (long)(16 * w + l15) * 256 + quad * 8;
    float s = 0.f;
#pragma unroll
    for (int ks = 0; ks < 8; ks++) {
      bfx8 kv = *(const bfx8*)(krow + ks * 32);
#pragma unroll
      for (int j = 0; j < 8; j++) s += (float)qf[ks][j] * (float)kv[j];
    }
    s += __shfl_xor(s, 16);
    s += __shfl_xor(s, 32);
    ps_l = __expf(clampf(s * 0.0625f, 30.f));
  }

  f32x4 acc[16];
#pragma unroll
  for (int i = 0; i < 16; i++) acc[i] = (f32x4){0.f, 0.f, 0.f, 0.f};
  float den[4] = {0.f, 0.f, 0.f, 0.f};

  for (int sc = 0; sc < 128; sc++) {
    __syncthreads();
#pragma unroll
    for (int rep = 0; rep < 4; rep++) {
      int idx = rep * 256 + tid;          // 0..1023
      // K chunk: [s][d] rows (coalesced, evenly-spread b128 writes)
      int s = idx >> 5;
      int g = idx & 31;
      *(bfx8*)&lk[s][g * 8] = *(const bfx8*)(ik + kvbase + (long)(sc * 32 + s) * 256 + g * 8);
      // V^T chunk: pure linear 16 KB copy (zero-conflict)
      *(bfx8*)&lvt[idx * 8] = *(const bfx8*)(ivT + vtbase + (long)sc * 8192 + idx * 8);
    }
    __syncthreads();

    // S = Q K^T
    f32x4 sacc[2];
    sacc[0] = (f32x4){0.f, 0.f, 0.f, 0.f};
    sacc[1] = (f32x4){0.f, 0.f, 0.f, 0.f};
#pragma unroll
    for (int ks = 0; ks < 8; ks++) {
      bfx8 b0 = *(const bfx8*)&lk[l15][ks * 32 + quad * 8];
      bfx8 b1 = *(const bfx8*)&lk[16 + l15][ks * 32 + quad * 8];
      sacc[0] = MFMA16(qf[ks], b0, sacc[0]);
      sacc[1] = MFMA16(qf[ks], b1, sacc[1]);
    }

    // P = exp(S/16)
#pragma unroll
    for (int ct = 0; ct < 2; ct++) {
      float rs[4];
#pragma unroll
      for (int r = 0; r < 4; r++) {
        float p = __expf(clampf(sacc[ct][r] * 0.0625f, 30.f));
        rs[r] = p;
        lp[16 * w + quad * 4 + r][ct * 16 + l15] = (__bf16)p;
      }
#pragma unroll
      for (int r = 0; r < 4; r++) {
        float v = rs[r];
        v += __shfl_xor(v, 1);
        v += __shfl_xor(v, 2);
        v += __shfl_xor(v, 4);
        v += __shfl_xor(v, 8);
        den[r] += v;
      }
    }

    __syncthreads();

    // O += P V
    bfx8 pf = *(const bfx8*)&lp[16 * w + l15][quad * 8];
#pragma unroll
    for (int dt = 0; dt < 16; dt++) {
      bfx8 vf = *(const bfx8*)&lvt[(dt * 16 + l15) * 32 + quad * 8];
      acc[dt] = MFMA16(pf, vf, acc[dt]);
    }
  }

  // epilogue
#pragma unroll
  for (int r = 0; r < 4; r++) {
    int ml = 16 * w + quad * 4 + r;
    float ps = __shfl(ps_l, quad * 4 + r);
    float dinv = 1.f / (den[r] + ps);
    const __bf16* mvrow = mv + mbase + (long)ml * 256;
    __bf16* crow = concat + ((long)(b * 1024 + m0 + ml)) * 2048 + h * 256;
#pragma unroll
    for (int dt = 0; dt < 16; dt++) {
      int d = dt * 16 + l15;
      float o = clampf((acc[dt][r] + ps * (float)mvrow[d]) * dinv, 60000.f);
      crow[d] = (__bf16)o;
    }
  }
}

// ---------------- LayerNorm with residual ----------------
__global__ __launch_bounds__(256)
void ln_kernel(const __bf16* __restrict__ a, const float* __restrict__ res,
               const float* __restrict__ g, const float* __restrict__ beta,
               __bf16* __restrict__ outb, float* __restrict__ outf) {
  int row  = blockIdx.x * 4 + (threadIdx.x >> 6);
  int lane = threadIdx.x & 63;
  const __bf16* ar = a   + (long)row * 256;
  const float*  rr = res + (long)row * 256;
  bfx4  av = *(const bfx4*)(ar + lane * 4);
  f32x4 rv = *(const f32x4*)(rr + lane * 4);
  float v[4], s1 = 0.f, s2 = 0.f;
#pragma unroll
  for (int i = 0; i < 4; i++) {
    v[i] = clampf((float)av[i] + rv[i], 30000.f);
    s1 += v[i];
    s2 += v[i] * v[i];
  }
#pragma unroll
  for (int off = 32; off >= 1; off >>= 1) {
    s1 += __shfl_xor(s1, off);
    s2 += __shfl_xor(s2, off);
  }
  float mean = s1 * (1.f / 256.f);
  float var  = fmaxf(s2 * (1.f / 256.f) - mean * mean, 0.f);
  float rstd = rsqrtf(var + 1e-6f);
#pragma unroll
  for (int i = 0; i < 4; i++) {
    int c = lane * 4 + i;
    float o = (v[i] - mean) * rstd * g[c] + beta[c];
    if (outb) outb[(long)row * 256 + c] = (__bf16)o;
    if (outf) outf[(long)row * 256 + c] = o;
  }
}

// ---------------- elementwise multiply ----------------
__global__ void mul_kernel(const __bf16* __restrict__ a, const __bf16* __restrict__ b,
                           __bf16* __restrict__ o, int n8) {
  int i = blockIdx.x * 256 + threadIdx.x;
  if (i < n8) {
    bfx8 x = *(const bfx8*)(a + (long)i * 8);
    bfx8 y = *(const bfx8*)(b + (long)i * 8);
    bfx8 z;
#pragma unroll
    for (int j = 0; j < 8; j++) z[j] = (__bf16)clampf((float)x[j] * (float)y[j], 60000.f);
    *(bfx8*)(o + (long)i * 8) = z;
  }
}

extern "C" void kernel_launch(void* const* d_in, const int* in_sizes, int n_in,
                              void* d_out, int out_size, void* d_ws, size_t ws_size,
                              hipStream_t stream) {
  const float* state  = (const float*)d_in[0];
  const float* input  = (const float*)d_in[1];
  const float* Wk     = (const float*)d_in[2];
  const float* bk     = (const float*)d_in[3];
  const float* Wv     = (const float*)d_in[4];
  const float* bv     = (const float*)d_in[5];
  const float* Wq     = (const float*)d_in[6];
  const float* bq     = (const float*)d_in[7];
  const float* Wo     = (const float*)d_in[8];
  const float* bo     = (const float*)d_in[9];
  const float* ln1g   = (const float*)d_in[10];
  const float* ln1b   = (const float*)d_in[11];
  const float* W_in   = (const float*)d_in[12];
  const float* b_in   = (const float*)d_in[13];
  const float* Wg_nl  = (const float*)d_in[14];
  const float* bg_nl  = (const float*)d_in[15];
  const float* Wg_l   = (const float*)d_in[16];
  const float* bg_l   = (const float*)d_in[17];
  const float* Wg_o   = (const float*)d_in[18];
  const float* bg_o   = (const float*)d_in[19];
  const float* ln2g   = (const float*)d_in[20];
  const float* ln2b   = (const float*)d_in[21];
  float* out = (float*)d_out;

  const size_t needed_elems = 28442624;
  if (ws_size < needed_elems * sizeof(__bf16)) return;

  __bf16* ws = (__bf16*)d_ws;
  size_t off = 0;
  auto alloc = [&](size_t n) { __bf16* p = ws + off; off += n; return p; };
  __bf16* Wkt    = alloc(65536);
  __bf16* Wvt    = alloc(65536);
  __bf16* Wqt    = alloc(524288);
  __bf16* Wot    = alloc(524288);
  __bf16* ik     = alloc(4194304);   // [4*4096,256]
  __bf16* ivT    = alloc(4194304);   // [4][128][256][32] chunk-transposed V
  __bf16* mk     = alloc(1048576);
  __bf16* mv     = alloc(1048576);
  __bf16* qbuf   = alloc(8388608);   // [8][4096][256]
  __bf16* concat = alloc(8388608);   // [4096][2048]
  // FFN-phase aliases over dead attention buffers
  __bf16* attn_o = mk;
  __bf16* x      = mv;
  __bf16* hbuf   = ik;
  __bf16* t1     = ivT;
  __bf16* t2     = qbuf;
  __bf16* gbuf   = qbuf + 4194304;
  __bf16* W_int  = concat;
  __bf16* Wg_nlt = concat + 262144;
  __bf16* Wg_lt  = concat + 1310720;
  __bf16* Wg_ot  = concat + 2359296;
  __bf16* ff     = concat + 2621440;
  float*  xf     = (float*)(concat + 3670016);

  dim3 blk(256);

  transpose_k<<<dim3(256, 1), blk, 0, stream>>>(Wk, Wkt, 256, 256);
  transpose_k<<<dim3(256, 1), blk, 0, stream>>>(Wv, Wvt, 256, 256);
  transpose_k<<<dim3(256, 8), blk, 0, stream>>>(Wq, Wqt, 256, 256);
  transpose_k<<<dim3(2048, 1), blk, 0, stream>>>(Wo, Wot, 2048, 256);

  gemm_bt<<<dim3(128, 2), blk, 0, stream>>>(nullptr, input, Wkt, bk, ik, 16384, 256, 256, 0, 0, 0, 0, 0, 0);
  gemm_bt<<<dim3(128, 2), blk, 0, stream>>>(nullptr, input, Wvt, bv, ivT, 16384, 256, 256, 0, 2, 0, 0, 0, 0);
  gemm_bt<<<dim3(32, 2), blk, 0, stream>>>(nullptr, state, Wkt, bk, mk, 4096, 256, 256, 0, 0, 0, 0, 0, 0);
  gemm_bt<<<dim3(32, 2), blk, 0, stream>>>(nullptr, state, Wvt, bv, mv, 4096, 256, 256, 0, 0, 0, 0, 0, 0);
  gemm_bt<<<dim3(32, 2, 8), blk, 0, stream>>>(nullptr, state, Wqt, bq, qbuf, 4096, 256, 256, 0, 0,
                                              0, 65536, 256, 1048576);

  attn_kernel<<<dim3(16, 4, 8), blk, 0, stream>>>(qbuf, ik, ivT, mk, mv, concat);

  gemm_bt<<<dim3(32, 2), blk, 0, stream>>>(concat, nullptr, Wot, bo, attn_o, 4096, 256, 2048, 0, 0, 0, 0, 0, 0);
  ln_kernel<<<dim3(1024), blk, 0, stream>>>(attn_o, state, ln1g, ln1b, x, xf);

  transpose_k<<<dim3(1024, 1), blk, 0, stream>>>(W_in, W_int, 256, 1024);
  transpose_k<<<dim3(4096, 1), blk, 0, stream>>>(Wg_nl, Wg_nlt, 1024, 1024);
  transpose_k<<<dim3(4096, 1), blk, 0, stream>>>(Wg_l, Wg_lt, 1024, 1024);
  transpose_k<<<dim3(1024, 1), blk, 0, stream>>>(Wg_o, Wg_ot, 1024, 256);

  gemm_bt<<<dim3(32, 8), blk, 0, stream>>>(x, nullptr, W_int, b_in, hbuf, 4096, 1024, 256, 1, 0, 0, 0, 0, 0);
  gemm_bt<<<dim3(32, 8), blk, 0, stream>>>(hbuf, nullptr, Wg_nlt, bg_nl, t1, 4096, 1024, 1024, 1, 0, 0, 0, 0, 0);
  gemm_bt<<<dim3(32, 8), blk, 0, stream>>>(hbuf, nullptr, Wg_lt, bg_l, t2, 4096, 1024, 1024, 0, 0, 0, 0, 0, 0);
  mul_kernel<<<dim3(2048), blk, 0, stream>>>(t1, t2, gbuf, 524288);
  gemm_bt<<<dim3(32, 2), blk, 0, stream>>>(gbuf, nullptr, Wg_ot, bg_o, ff, 4096, 256, 1024, 0, 0, 0, 0, 0, 0);
  ln_kernel<<<dim3(1024), blk, 0, stream>>>(ff, xf, ln2g, ln2b, nullptr, out);
}

// Round 6
// 679.262 us; speedup vs baseline: 2.4351x; 1.2162x over previous
//
#include <hip/hip_runtime.h>
#include <hip/hip_bf16.h>

typedef __bf16 bfx8 __attribute__((ext_vector_type(8)));
typedef __bf16 bfx4 __attribute__((ext_vector_type(4)));
typedef float  f32x4 __attribute__((ext_vector_type(4)));

#define MFMA16(a,b,c) __builtin_amdgcn_mfma_f32_16x16x32_bf16((a),(b),(c),0,0,0)

// B=4, SM=1024, SI=4096, D=256, H=8, FF=1024
// External I/O: float32. Internal: bf16 operands + f32 accumulation.

// ---------------- merged attention-phase weight transposes (f32 -> bf16^T) ----------------
__global__ void trans_attn(const float* __restrict__ Wk, const float* __restrict__ Wv,
                           const float* __restrict__ Wq, const float* __restrict__ Wo,
                           __bf16* __restrict__ wkvqt, __bf16* __restrict__ wot) {
  int i = blockIdx.x * 256 + threadIdx.x;
  if (i < 65536) {                               // Wk [256][256]
    int r = i >> 8, c = i & 255;
    wkvqt[c * 256 + r] = (__bf16)Wk[i];
  } else if (i < 131072) {                       // Wv
    int e = i - 65536, r = e >> 8, c = e & 255;
    wkvqt[65536 + c * 256 + r] = (__bf16)Wv[e];
  } else if (i < 655360) {                       // Wq [8][256][256]
    int e = i - 131072, mat = e >> 16, rc = e & 65535, r = rc >> 8, c = rc & 255;
    wkvqt[131072 + mat * 65536 + c * 256 + r] = (__bf16)Wq[e];
  } else {                                       // Wo [2048][256]
    int e = i - 655360, r = e >> 8, c = e & 255;
    wot[c * 2048 + r] = (__bf16)Wo[e];
  }
}

// ---------------- merged FFN-phase weight transposes ----------------
__global__ void trans_ffn(const float* __restrict__ W_in, const float* __restrict__ Wg_nl,
                          const float* __restrict__ Wg_l, const float* __restrict__ Wg_o,
                          __bf16* __restrict__ dst) {
  int i = blockIdx.x * 256 + threadIdx.x;
  if (i < 262144) {                              // W_in [256][1024]
    int r = i >> 10, c = i & 1023;
    dst[c * 256 + r] = (__bf16)W_in[i];
  } else if (i < 1310720) {                      // Wg_nl [1024][1024]
    int e = i - 262144, r = e >> 10, c = e & 1023;
    dst[262144 + c * 1024 + r] = (__bf16)Wg_nl[e];
  } else if (i < 2359296) {                      // Wg_l
    int e = i - 1310720, r = e >> 10, c = e & 1023;
    dst[1310720 + c * 1024 + r] = (__bf16)Wg_l[e];
  } else {                                       // Wg_o [1024][256]
    int e = i - 2359296, r = e >> 8, c = e & 255;
    dst[2359296 + c * 1024 + r] = (__bf16)Wg_o[e];
  }
}

// ---------------- GEMM: C[M,N] = act(X[M,K] @ Wt[N,K]^T + bias) ----------------
// xmode: 0 = bf16 X (stride K); 1 = f32 X (stride K); 2 = gated bf16 (stride 2048,
//        x = X[m][k] * X[m][k+1024], relu already applied to first half upstream)
// mode:  0 = plain C[m*N+n] (act flag); 4 = K|V split (C=ik rowmajor256, C2=ivT chunked);
//        5 = K|V|Q split (C=mk, C2=mv, C3=qbuf); 6 = dual-act t12 (relu iff n<1024)
__global__ __launch_bounds__(256)
void gemm_bt(const __bf16* __restrict__ Xb, const float* __restrict__ Xf,
             const __bf16* __restrict__ Wt,
             const float* __restrict__ b1, const float* __restrict__ b2,
             const float* __restrict__ b3,
             __bf16* __restrict__ C, __bf16* __restrict__ C2, __bf16* __restrict__ C3,
             int M, int N, int K, int xmode, int mode, int act) {
  __shared__ __bf16 xs[128][72];
  __shared__ __bf16 wsm[128][72];

  const int tid  = threadIdx.x;
  const int lane = tid & 63;
  const int w    = tid >> 6;
  const int l15  = lane & 15;
  const int quad = lane >> 4;
  const int wm   = (w >> 1) * 64;
  const int wn   = (w & 1) * 64;
  const int m0   = blockIdx.x * 128;
  const int n0   = blockIdx.y * 128;

  f32x4 acc[4][4];
#pragma unroll
  for (int i = 0; i < 4; i++)
#pragma unroll
    for (int j = 0; j < 4; j++) acc[i][j] = (f32x4){0.f, 0.f, 0.f, 0.f};

  for (int kk = 0; kk < K; kk += 64) {
    __syncthreads();
#pragma unroll
    for (int rep = 0; rep < 4; rep++) {
      int idx = rep * 256 + tid;
      int row = idx >> 3;
      int g   = idx & 7;
      if (xmode == 1) {
        const float* p = Xf + (long)(m0 + row) * K + kk + g * 8;
        f32x4 a0 = *(const f32x4*)p;
        f32x4 a1 = *(const f32x4*)(p + 4);
        bfx8 v;
#pragma unroll
        for (int j = 0; j < 4; j++) { v[j] = (__bf16)a0[j]; v[4 + j] = (__bf16)a1[j]; }
        *(bfx8*)&xs[row][g * 8] = v;
      } else if (xmode == 2) {
        const __bf16* p = Xb + (long)(m0 + row) * 2048 + kk + g * 8;
        bfx8 a = *(const bfx8*)p;
        bfx8 bb = *(const bfx8*)(p + 1024);
        bfx8 v;
#pragma unroll
        for (int j = 0; j < 8; j++) v[j] = (__bf16)((float)a[j] * (float)bb[j]);
        *(bfx8*)&xs[row][g * 8] = v;
      } else {
        *(bfx8*)&xs[row][g * 8] = *(const bfx8*)(Xb + (long)(m0 + row) * K + kk + g * 8);
      }
      *(bfx8*)&wsm[row][g * 8] = *(const bfx8*)(Wt + (long)(n0 + row) * K + kk + g * 8);
    }
    __syncthreads();
#pragma unroll
    for (int ks = 0; ks < 2; ks++) {
      bfx8 af[4], bf_[4];
#pragma unroll
      for (int i = 0; i < 4; i++) af[i]  = *(const bfx8*)&xs[wm + 16 * i + l15][ks * 32 + quad * 8];
#pragma unroll
      for (int j = 0; j < 4; j++) bf_[j] = *(const bfx8*)&wsm[wn + 16 * j + l15][ks * 32 + quad * 8];
#pragma unroll
      for (int i = 0; i < 4; i++)
#pragma unroll
        for (int j = 0; j < 4; j++) acc[i][j] = MFMA16(af[i], bf_[j], acc[i][j]);
    }
  }

#pragma unroll
  for (int j = 0; j < 4; j++) {
    int n = n0 + wn + 16 * j + l15;
    float bv;
    if (mode == 4)      bv = (n < 256) ? b1[n] : b2[n - 256];
    else if (mode == 5) bv = (n < 256) ? b1[n] : (n < 512) ? b2[n - 256] : b3[n - 512];
    else if (mode == 6) bv = (n < 1024) ? b1[n] : b2[n - 1024];
    else                bv = b1[n];
#pragma unroll
    for (int i = 0; i < 4; i++) {
#pragma unroll
      for (int r = 0; r < 4; r++) {
        int m = m0 + wm + 16 * i + quad * 4 + r;   // C/D layout: row = quad*4+reg
        float v = acc[i][j][r] + bv;
        if (mode == 6) { if (n < 1024) v = fmaxf(v, 0.f); }
        else if (act == 1) v = fmaxf(v, 0.f);
        if (mode == 4) {
          if (n < 256) C[(long)m * 256 + n] = (__bf16)v;
          else {
            int bb_ = m >> 12, si = m & 4095;
            C2[((long)(bb_ * 128 + (si >> 5)) * 256 + (n - 256)) * 32 + (si & 31)] = (__bf16)v;
          }
        } else if (mode == 5) {
          if (n < 256)      C[(long)m * 256 + n] = (__bf16)v;
          else if (n < 512) C2[(long)m * 256 + (n - 256)] = (__bf16)v;
          else {
            int nn = n - 512, hh = nn >> 8, dd = nn & 255;
            C3[(long)hh * 1048576 + (long)m * 256 + dd] = (__bf16)v;
          }
        } else {
          C[(long)m * N + n] = (__bf16)v;
        }
      }
    }
  }
}

// ---------------- fused multi-query attention ----------------
// grid (SM/64, B, H), block 256 (4 waves). Wave w owns Q rows 16w..16w+15.
// Double-buffered V^T (stride 40 -> 2-way-free reads), register-prefetched K/V,
// denominator via ones-fragment MFMA accumulated in accd.
__global__ __launch_bounds__(256)
void attn_kernel(const __bf16* __restrict__ qb,   // [H][B*SM][256]
                 const __bf16* __restrict__ ik,   // [B*SI][256]
                 const __bf16* __restrict__ ivT,  // [B][128][256][32]
                 const __bf16* __restrict__ mk,   // [B*SM][256]
                 const __bf16* __restrict__ mv,   // [B*SM][256]
                 __bf16* __restrict__ concat) {   // [B*SM][2048]
  __shared__ __bf16 lk[32][264];        // K chunk [s][d] (+8 pad: 2-way-free reads)
  __shared__ __bf16 lvt[2][256][40];    // V^T chunks [d][s], stride 40 (2-way-free)
  __shared__ __bf16 lp[64][40];         // P tile [m][s], wave-private rows

  const int tid  = threadIdx.x;
  const int lane = tid & 63;
  const int w    = tid >> 6;
  const int l15  = lane & 15;
  const int quad = lane >> 4;

  const int m0 = blockIdx.x * 64;
  const int b  = blockIdx.y;
  const int h  = blockIdx.z;

  const long qbase  = ((long)h * 4096 + b * 1024 + m0) * 256;
  const long kvbase = (long)b * 4096 * 256;
  const long vtbase = (long)b * 128 * 8192;
  const long mbase  = ((long)b * 1024 + m0) * 256;

  bfx8 qf[8];
  {
    const __bf16* qrow = qb + qbase + (long)(16 * w + l15) * 256 + quad * 8;
#pragma unroll
    for (int ks = 0; ks < 8; ks++) qf[ks] = *(const bfx8*)(qrow + ks * 32);
  }

  // self score for row 16w+l15 (registers only)
  float ps_l;
  {
    const __bf16* krow = mk + mbase + (long)(16 * w + l15) * 256 + quad * 8;
    float s = 0.f;
#pragma unroll
    for (int ks = 0; ks < 8; ks++) {
      bfx8 kv = *(const bfx8*)(krow + ks * 32);
#pragma unroll
      for (int j = 0; j < 8; j++) s += (float)qf[ks][j] * (float)kv[j];
    }
    s += __shfl_xor(s, 16);
    s += __shfl_xor(s, 32);
    ps_l = __expf(fminf(s * 0.0625f, 30.f));
  }

  bfx8 onesf;
#pragma unroll
  for (int j = 0; j < 8; j++) onesf[j] = (__bf16)1.0f;

  f32x4 acc[16];
#pragma unroll
  for (int i = 0; i < 16; i++) acc[i] = (f32x4){0.f, 0.f, 0.f, 0.f};
  f32x4 accd = (f32x4){0.f, 0.f, 0.f, 0.f};

  // prologue: stage chunk 0
#pragma unroll
  for (int rep = 0; rep < 4; rep++) {
    int idx = rep * 256 + tid;
    *(bfx8*)&lk[idx >> 5][(idx & 31) * 8] =
        *(const bfx8*)(ik + kvbase + (long)(idx >> 5) * 256 + (idx & 31) * 8);
    *(bfx8*)&lvt[0][idx >> 2][(idx & 3) * 8] = *(const bfx8*)(ivT + vtbase + (long)idx * 8);
  }
  __syncthreads();

  for (int sc = 0; sc < 128; sc++) {
    const int cur = sc & 1;
    bfx8 kreg[4], vreg[4];
    if (sc < 127) {
      const long kb = kvbase + (long)(sc + 1) * 8192;
      const long vb = vtbase + (long)(sc + 1) * 8192;
#pragma unroll
      for (int rep = 0; rep < 4; rep++) {
        int idx = rep * 256 + tid;
        kreg[rep] = *(const bfx8*)(ik + kb + (long)(idx >> 5) * 256 + (idx & 31) * 8);
        vreg[rep] = *(const bfx8*)(ivT + vb + (long)idx * 8);
      }
    }

    // S = Q K^T (from lk)
    f32x4 s0v = (f32x4){0.f, 0.f, 0.f, 0.f};
    f32x4 s1v = (f32x4){0.f, 0.f, 0.f, 0.f};
#pragma unroll
    for (int ks = 0; ks < 8; ks++) {
      bfx8 b0 = *(const bfx8*)&lk[l15][ks * 32 + quad * 8];
      bfx8 b1 = *(const bfx8*)&lk[16 + l15][ks * 32 + quad * 8];
      s0v = MFMA16(qf[ks], b0, s0v);
      s1v = MFMA16(qf[ks], b1, s1v);
    }
    __syncthreads();               // all QK reads of lk complete

    if (sc < 127) {                // overwrite lk (next chunk) + fill other lvt buffer
#pragma unroll
      for (int rep = 0; rep < 4; rep++) {
        int idx = rep * 256 + tid;
        *(bfx8*)&lk[idx >> 5][(idx & 31) * 8] = kreg[rep];
        *(bfx8*)&lvt[cur ^ 1][idx >> 2][(idx & 3) * 8] = vreg[rep];
      }
    }

    // P = exp(S/16) -> lp (wave-private rows; same-wave DS order)
#pragma unroll
    for (int r = 0; r < 4; r++) {
      lp[16 * w + quad * 4 + r][l15]      = (__bf16)__expf(fminf(s0v[r] * 0.0625f, 30.f));
      lp[16 * w + quad * 4 + r][16 + l15] = (__bf16)__expf(fminf(s1v[r] * 0.0625f, 30.f));
    }

    // O += P V ; den += P @ ones
    bfx8 pf = *(const bfx8*)&lp[16 * w + l15][quad * 8];
    accd = MFMA16(pf, onesf, accd);
#pragma unroll
    for (int dt = 0; dt < 16; dt++) {
      bfx8 vf = *(const bfx8*)&lvt[cur][dt * 16 + l15][quad * 8];
      acc[dt] = MFMA16(pf, vf, acc[dt]);
    }
    __syncthreads();               // staged lk/lvt visible; lvt[cur] reads done
  }

  // epilogue: add self term, normalize, scatter into concat[b,m,h*256+d]
#pragma unroll
  for (int r = 0; r < 4; r++) {
    int ml = 16 * w + quad * 4 + r;
    float ps = __shfl(ps_l, quad * 4 + r);
    float dinv = 1.f / (accd[r] + ps);
    const __bf16* mvrow = mv + mbase + (long)ml * 256;
    __bf16* crow = concat + ((long)(b * 1024 + m0 + ml)) * 2048 + h * 256;
#pragma unroll
    for (int dt = 0; dt < 16; dt++) {
      int d = dt * 16 + l15;
      crow[d] = (__bf16)((acc[dt][r] + ps * (float)mvrow[d]) * dinv);
    }
  }
}

// ---------------- LayerNorm with residual: out = LN(a + res)*g + b ----------------
__global__ __launch_bounds__(256)
void ln_kernel(const __bf16* __restrict__ a, const float* __restrict__ res,
               const float* __restrict__ g, const float* __restrict__ beta,
               __bf16* __restrict__ outb, float* __restrict__ outf) {
  int row  = blockIdx.x * 4 + (threadIdx.x >> 6);
  int lane = threadIdx.x & 63;
  const __bf16* ar = a   + (long)row * 256;
  const float*  rr = res + (long)row * 256;
  bfx4  av = *(const bfx4*)(ar + lane * 4);
  f32x4 rv = *(const f32x4*)(rr + lane * 4);
  float v[4], s1 = 0.f, s2 = 0.f;
#pragma unroll
  for (int i = 0; i < 4; i++) {
    v[i] = (float)av[i] + rv[i];
    s1 += v[i];
    s2 += v[i] * v[i];
  }
#pragma unroll
  for (int off = 32; off >= 1; off >>= 1) {
    s1 += __shfl_xor(s1, off);
    s2 += __shfl_xor(s2, off);
  }
  float mean = s1 * (1.f / 256.f);
  float var  = fmaxf(s2 * (1.f / 256.f) - mean * mean, 0.f);
  float rstd = rsqrtf(var + 1e-6f);
#pragma unroll
  for (int i = 0; i < 4; i++) {
    int c = lane * 4 + i;
    float o = (v[i] - mean) * rstd * g[c] + beta[c];
    if (outb) outb[(long)row * 256 + c] = (__bf16)o;
    if (outf) outf[(long)row * 256 + c] = o;
  }
}

extern "C" void kernel_launch(void* const* d_in, const int* in_sizes, int n_in,
                              void* d_out, int out_size, void* d_ws, size_t ws_size,
                              hipStream_t stream) {
  const float* state  = (const float*)d_in[0];
  const float* input  = (const float*)d_in[1];
  const float* Wk     = (const float*)d_in[2];
  const float* bk     = (const float*)d_in[3];
  const float* Wv     = (const float*)d_in[4];
  const float* bv     = (const float*)d_in[5];
  const float* Wq     = (const float*)d_in[6];
  const float* bq     = (const float*)d_in[7];
  const float* Wo     = (const float*)d_in[8];
  const float* bo     = (const float*)d_in[9];
  const float* ln1g   = (const float*)d_in[10];
  const float* ln1b   = (const float*)d_in[11];
  const float* W_in   = (const float*)d_in[12];
  const float* b_in   = (const float*)d_in[13];
  const float* Wg_nl  = (const float*)d_in[14];
  const float* bg_nl  = (const float*)d_in[15];
  const float* Wg_l   = (const float*)d_in[16];
  const float* bg_l   = (const float*)d_in[17];
  const float* Wg_o   = (const float*)d_in[18];
  const float* bg_o   = (const float*)d_in[19];
  const float* ln2g   = (const float*)d_in[20];
  const float* ln2b   = (const float*)d_in[21];
  float* out = (float*)d_out;

  const size_t needed_elems = 28442624;   // 56.9 MB, proven budget
  if (ws_size < needed_elems * sizeof(__bf16)) return;

  __bf16* ws = (__bf16*)d_ws;
  size_t off = 0;
  auto alloc = [&](size_t n) { __bf16* p = ws + off; off += n; return p; };
  __bf16* Wkvqt  = alloc(655360);    // [2560][256]: Wk^T | Wv^T | Wq^T(8)
  __bf16* Wot    = alloc(524288);    // [256][2048]
  __bf16* ik     = alloc(4194304);   // [16384][256]
  __bf16* ivT    = alloc(4194304);   // [4][128][256][32]
  __bf16* mk     = alloc(1048576);   // [4096][256]
  __bf16* mv     = alloc(1048576);
  __bf16* qbuf   = alloc(8388608);   // [8][4096][256]
  __bf16* concat = alloc(8388608);   // [4096][2048]
  // FFN-phase aliases over dead attention buffers
  __bf16* attn_o = mk;
  __bf16* x      = mv;
  __bf16* hbuf   = ik;               // [4096][1024]
  __bf16* t12    = qbuf;             // [4096][2048]
  __bf16* Wffn   = concat;           // W_in^T | Wg_nl^T | Wg_l^T | Wg_o^T (2621440)
  __bf16* ff     = concat + 2621440; // [4096][256]
  float*  xf     = (float*)(concat + 3670016); // [4096][256] f32 residual

  dim3 blk(256);

  trans_attn<<<dim3(4608), blk, 0, stream>>>(Wk, Wv, Wq, Wo, Wkvqt, Wot);

  // fused K|V input projection: N=512
  gemm_bt<<<dim3(128, 4), blk, 0, stream>>>(nullptr, input, Wkvqt, bk, bv, nullptr,
                                            ik, ivT, nullptr, 16384, 512, 256, 1, 4, 0);
  // fused K|V|Q state projection: N=2560
  gemm_bt<<<dim3(32, 20), blk, 0, stream>>>(nullptr, state, Wkvqt, bk, bv, bq,
                                            mk, mv, qbuf, 4096, 2560, 256, 1, 5, 0);

  attn_kernel<<<dim3(16, 4, 8), blk, 0, stream>>>(qbuf, ik, ivT, mk, mv, concat);

  gemm_bt<<<dim3(32, 2), blk, 0, stream>>>(concat, nullptr, Wot, bo, nullptr, nullptr,
                                           attn_o, nullptr, nullptr, 4096, 256, 2048, 0, 0, 0);
  ln_kernel<<<dim3(1024), blk, 0, stream>>>(attn_o, state, ln1g, ln1b, x, xf);

  trans_ffn<<<dim3(10240), blk, 0, stream>>>(W_in, Wg_nl, Wg_l, Wg_o, Wffn);

  gemm_bt<<<dim3(32, 8), blk, 0, stream>>>(x, nullptr, Wffn, b_in, nullptr, nullptr,
                                           hbuf, nullptr, nullptr, 4096, 1024, 256, 0, 0, 1);
  // fused Wg_nl|Wg_l: N=2048, relu on first half
  gemm_bt<<<dim3(32, 16), blk, 0, stream>>>(hbuf, nullptr, Wffn + 262144, bg_nl, bg_l, nullptr,
                                            t12, nullptr, nullptr, 4096, 2048, 1024, 0, 6, 0);
  // Wg_o with gating fused into the stager
  gemm_bt<<<dim3(32, 2), blk, 0, stream>>>(t12, nullptr, Wffn + 2359296, bg_o, nullptr, nullptr,
                                           ff, nullptr, nullptr, 4096, 256, 1024, 2, 0, 0);
  ln_kernel<<<dim3(1024), blk, 0, stream>>>(ff, xf, ln2g, ln2b, nullptr, out);
}

// Round 7
// 577.025 us; speedup vs baseline: 2.8666x; 1.1772x over previous
//
#include <hip/hip_runtime.h>
#include <hip/hip_bf16.h>

typedef __bf16 bfx8 __attribute__((ext_vector_type(8)));
typedef __bf16 bfx4 __attribute__((ext_vector_type(4)));
typedef float  f32x4 __attribute__((ext_vector_type(4)));
typedef float  f32x16 __attribute__((ext_vector_type(16)));

#define MFMA16(a,b,c) __builtin_amdgcn_mfma_f32_16x16x32_bf16((a),(b),(c),0,0,0)
#define MFMA32(a,b,c) __builtin_amdgcn_mfma_f32_32x32x16_bf16((a),(b),(c),0,0,0)

// B=4, SM=1024, SI=4096, D=256, H=8, FF=1024
// External I/O: float32. Internal: bf16 operands + f32 accumulation.

// ---------------- merged attention-phase weight transposes (f32 -> bf16^T) ----------------
__global__ void trans_attn(const float* __restrict__ Wk, const float* __restrict__ Wv,
                           const float* __restrict__ Wq, const float* __restrict__ Wo,
                           __bf16* __restrict__ wkvqt, __bf16* __restrict__ wot) {
  int i = blockIdx.x * 256 + threadIdx.x;
  if (i < 65536) {                               // Wk [256][256]
    int r = i >> 8, c = i & 255;
    wkvqt[c * 256 + r] = (__bf16)Wk[i];
  } else if (i < 131072) {                       // Wv
    int e = i - 65536, r = e >> 8, c = e & 255;
    wkvqt[65536 + c * 256 + r] = (__bf16)Wv[e];
  } else if (i < 655360) {                       // Wq [8][256][256]
    int e = i - 131072, mat = e >> 16, rc = e & 65535, r = rc >> 8, c = rc & 255;
    wkvqt[131072 + mat * 65536 + c * 256 + r] = (__bf16)Wq[e];
  } else {                                       // Wo [2048][256]
    int e = i - 655360, r = e >> 8, c = e & 255;
    wot[c * 2048 + r] = (__bf16)Wo[e];
  }
}

// ---------------- merged FFN-phase weight transposes ----------------
__global__ void trans_ffn(const float* __restrict__ W_in, const float* __restrict__ Wg_nl,
                          const float* __restrict__ Wg_l, const float* __restrict__ Wg_o,
                          __bf16* __restrict__ dst) {
  int i = blockIdx.x * 256 + threadIdx.x;
  if (i < 262144) {                              // W_in [256][1024]
    int r = i >> 10, c = i & 1023;
    dst[c * 256 + r] = (__bf16)W_in[i];
  } else if (i < 1310720) {                      // Wg_nl [1024][1024]
    int e = i - 262144, r = e >> 10, c = e & 1023;
    dst[262144 + c * 1024 + r] = (__bf16)Wg_nl[e];
  } else if (i < 2359296) {                      // Wg_l
    int e = i - 1310720, r = e >> 10, c = e & 1023;
    dst[1310720 + c * 1024 + r] = (__bf16)Wg_l[e];
  } else {                                       // Wg_o [1024][256]
    int e = i - 2359296, r = e >> 8, c = e & 255;
    dst[2359296 + c * 1024 + r] = (__bf16)Wg_o[e];
  }
}

// ---------------- GEMM: C[M,N] = act(X[M,K] @ Wt[N,K]^T + bias) ----------------
// xmode: 0 bf16 X (row stride Kfull); 1 f32 X; 2 gated bf16 (stride 2048, x=a*b pairs k,k+1024)
// mode: 0 plain; 4 K|V split; 5 K|V|Q split; 6 dual-act (relu iff n<1024);
//       7 split-K f32 partials: Cf[z*M*N + m*N + n] (bias added in z==0 slice)
__global__ __launch_bounds__(256)
void gemm_bt(const __bf16* __restrict__ Xb, const float* __restrict__ Xf,
             const __bf16* __restrict__ Wt,
             const float* __restrict__ b1, const float* __restrict__ b2,
             const float* __restrict__ b3,
             __bf16* __restrict__ C, __bf16* __restrict__ C2, __bf16* __restrict__ C3,
             float* __restrict__ Cf,
             int M, int N, int Kfull, int kspan, int xmode, int mode, int act) {
  __shared__ __bf16 xs[128][72];
  __shared__ __bf16 wsm[128][72];

  const int tid  = threadIdx.x;
  const int lane = tid & 63;
  const int w    = tid >> 6;
  const int l15  = lane & 15;
  const int quad = lane >> 4;
  const int wm   = (w >> 1) * 64;
  const int wn   = (w & 1) * 64;
  const int m0   = blockIdx.x * 128;
  const int n0   = blockIdx.y * 128;
  const int k0   = (mode == 7) ? blockIdx.z * kspan : 0;

  f32x4 acc[4][4];
#pragma unroll
  for (int i = 0; i < 4; i++)
#pragma unroll
    for (int j = 0; j < 4; j++) acc[i][j] = (f32x4){0.f, 0.f, 0.f, 0.f};

  for (int kk = k0; kk < k0 + kspan; kk += 64) {
    __syncthreads();
#pragma unroll
    for (int rep = 0; rep < 4; rep++) {
      int idx = rep * 256 + tid;
      int row = idx >> 3;
      int g   = idx & 7;
      if (xmode == 1) {
        const float* p = Xf + (long)(m0 + row) * Kfull + kk + g * 8;
        f32x4 a0 = *(const f32x4*)p;
        f32x4 a1 = *(const f32x4*)(p + 4);
        bfx8 v;
#pragma unroll
        for (int j = 0; j < 4; j++) { v[j] = (__bf16)a0[j]; v[4 + j] = (__bf16)a1[j]; }
        *(bfx8*)&xs[row][g * 8] = v;
      } else if (xmode == 2) {
        const __bf16* p = Xb + (long)(m0 + row) * 2048 + kk + g * 8;
        bfx8 a = *(const bfx8*)p;
        bfx8 bb = *(const bfx8*)(p + 1024);
        bfx8 v;
#pragma unroll
        for (int j = 0; j < 8; j++) v[j] = (__bf16)((float)a[j] * (float)bb[j]);
        *(bfx8*)&xs[row][g * 8] = v;
      } else {
        *(bfx8*)&xs[row][g * 8] = *(const bfx8*)(Xb + (long)(m0 + row) * Kfull + kk + g * 8);
      }
      *(bfx8*)&wsm[row][g * 8] = *(const bfx8*)(Wt + (long)(n0 + row) * Kfull + kk + g * 8);
    }
    __syncthreads();
#pragma unroll
    for (int ks = 0; ks < 2; ks++) {
      bfx8 af[4], bf_[4];
#pragma unroll
      for (int i = 0; i < 4; i++) af[i]  = *(const bfx8*)&xs[wm + 16 * i + l15][ks * 32 + quad * 8];
#pragma unroll
      for (int j = 0; j < 4; j++) bf_[j] = *(const bfx8*)&wsm[wn + 16 * j + l15][ks * 32 + quad * 8];
#pragma unroll
      for (int i = 0; i < 4; i++)
#pragma unroll
        for (int j = 0; j < 4; j++) acc[i][j] = MFMA16(af[i], bf_[j], acc[i][j]);
    }
  }

#pragma unroll
  for (int j = 0; j < 4; j++) {
    int n = n0 + wn + 16 * j + l15;
    float bv;
    if (mode == 4)      bv = (n < 256) ? b1[n] : b2[n - 256];
    else if (mode == 5) bv = (n < 256) ? b1[n] : (n < 512) ? b2[n - 256] : b3[n - 512];
    else if (mode == 6) bv = (n < 1024) ? b1[n] : b2[n - 1024];
    else if (mode == 7) bv = (blockIdx.z == 0) ? b1[n] : 0.f;
    else                bv = b1[n];
#pragma unroll
    for (int i = 0; i < 4; i++) {
#pragma unroll
      for (int r = 0; r < 4; r++) {
        int m = m0 + wm + 16 * i + quad * 4 + r;   // C/D layout: row = quad*4+reg
        float v = acc[i][j][r] + bv;
        if (mode == 6) { if (n < 1024) v = fmaxf(v, 0.f); }
        else if (act == 1) v = fmaxf(v, 0.f);
        if (mode == 4) {
          if (n < 256) C[(long)m * 256 + n] = (__bf16)v;
          else {
            int bb_ = m >> 12, si = m & 4095;
            C2[((long)(bb_ * 128 + (si >> 5)) * 256 + (n - 256)) * 32 + (si & 31)] = (__bf16)v;
          }
        } else if (mode == 5) {
          if (n < 256)      C[(long)m * 256 + n] = (__bf16)v;
          else if (n < 512) C2[(long)m * 256 + (n - 256)] = (__bf16)v;
          else {
            int nn = n - 512, hh = nn >> 8, dd = nn & 255;
            C3[(long)hh * 1048576 + (long)m * 256 + dd] = (__bf16)v;
          }
        } else if (mode == 7) {
          Cf[(long)blockIdx.z * M * N + (long)m * N + n] = v;
        } else {
          C[(long)m * N + n] = (__bf16)v;
        }
      }
    }
  }
}

// ---------------- fused multi-query attention (32x32 MFMA) ----------------
// grid (SM/128, B, H), block 256 (4 waves). Wave w owns Q rows w*32..w*32+31.
__global__ __launch_bounds__(256)
void attn_kernel(const __bf16* __restrict__ qb,   // [H][B*SM][256]
                 const __bf16* __restrict__ ik,   // [B*SI][256]
                 const __bf16* __restrict__ ivT,  // [B][128][256][32]
                 const __bf16* __restrict__ mk,   // [B*SM][256]
                 const __bf16* __restrict__ mv,   // [B*SM][256]
                 __bf16* __restrict__ concat) {   // [B*SM][2048]
  __shared__ __bf16 lk[32][264];        // K chunk [s][d]        (16.5 KB)
  __shared__ __bf16 lvt[2][256][40];    // V^T chunks [d][s]     (40 KB)
  __shared__ __bf16 lp[128][40];        // P tiles, 32 rows/wave (10 KB)

  const int tid  = threadIdx.x;
  const int lane = tid & 63;
  const int w    = tid >> 6;
  const int l31  = lane & 31;
  const int h    = lane >> 5;

  const int m0 = blockIdx.x * 128;
  const int b  = blockIdx.y;
  const int hh = blockIdx.z;
  const int mw = m0 + w * 32;             // this wave's first Q row

  const long qbase  = ((long)hh * 4096 + b * 1024 + mw) * 256;
  const long kvbase = (long)b * 4096 * 256;
  const long vtbase = (long)b * 128 * 8192;
  const long mbase  = ((long)b * 1024 + mw) * 256;

  // Q A-frags: lane holds A[m=l31][k = kt*16 + h*8 + j]
  bfx8 qf[16];
  {
    const __bf16* qrow = qb + qbase + (long)l31 * 256 + h * 8;
#pragma unroll
    for (int kt = 0; kt < 16; kt++) qf[kt] = *(const bfx8*)(qrow + kt * 16);
  }

  // self score for row l31 (halves hold complementary k-slices; xor-32 combines)
  float ps_l;
  {
    const __bf16* krow = mk + mbase + (long)l31 * 256 + h * 8;
    float s = 0.f;
#pragma unroll
    for (int kt = 0; kt < 16; kt++) {
      bfx8 kv = *(const bfx8*)(krow + kt * 16);
#pragma unroll
      for (int j = 0; j < 8; j++) s += (float)qf[kt][j] * (float)kv[j];
    }
    s += __shfl_xor(s, 32);
    ps_l = __expf(fminf(s * 0.0625f, 30.f));
  }

  bfx8 onesf;
#pragma unroll
  for (int j = 0; j < 8; j++) onesf[j] = (__bf16)1.0f;

  f32x16 oacc[8];
  f32x16 dacc;
#pragma unroll
  for (int i = 0; i < 16; i++) dacc[i] = 0.f;
#pragma unroll
  for (int dt = 0; dt < 8; dt++)
#pragma unroll
    for (int i = 0; i < 16; i++) oacc[dt][i] = 0.f;

  // prologue: stage chunk 0
#pragma unroll
  for (int rep = 0; rep < 4; rep++) {
    int idx = rep * 256 + tid;
    *(bfx8*)&lk[idx >> 5][(idx & 31) * 8] =
        *(const bfx8*)(ik + kvbase + (long)(idx >> 5) * 256 + (idx & 31) * 8);
    *(bfx8*)&lvt[0][idx >> 2][(idx & 3) * 8] = *(const bfx8*)(ivT + vtbase + (long)idx * 8);
  }
  __syncthreads();

  for (int sc = 0; sc < 128; sc++) {
    const int cur = sc & 1;
    bfx8 kreg[4], vreg[4];
    if (sc < 127) {
      const long kb = kvbase + (long)(sc + 1) * 8192;
      const long vb = vtbase + (long)(sc + 1) * 8192;
#pragma unroll
      for (int rep = 0; rep < 4; rep++) {
        int idx = rep * 256 + tid;
        kreg[rep] = *(const bfx8*)(ik + kb + (long)(idx >> 5) * 256 + (idx & 31) * 8);
        vreg[rep] = *(const bfx8*)(ivT + vb + (long)idx * 8);
      }
    }

    // S = Q K^T : D[m=q-row][n=key], 16 MFMA over k
    f32x16 sacc;
#pragma unroll
    for (int i = 0; i < 16; i++) sacc[i] = 0.f;
#pragma unroll
    for (int kt = 0; kt < 16; kt++) {
      bfx8 kf = *(const bfx8*)&lk[l31][kt * 16 + h * 8];
      sacc = MFMA32(qf[kt], kf, sacc);
    }
    __syncthreads();               // all QK reads of lk complete

    if (sc < 127) {                // stage next chunk (lk overwrite + other lvt buffer)
#pragma unroll
      for (int rep = 0; rep < 4; rep++) {
        int idx = rep * 256 + tid;
        *(bfx8*)&lk[idx >> 5][(idx & 31) * 8] = kreg[rep];
        *(bfx8*)&lvt[cur ^ 1][idx >> 2][(idx & 3) * 8] = vreg[rep];
      }
    }

    // P = exp(S/16) -> lp (C-layout rows; wave-private)
#pragma unroll
    for (int r = 0; r < 16; r++) {
      int row = (r & 3) + 8 * (r >> 2) + 4 * h;
      lp[w * 32 + row][l31] = (__bf16)__expf(fminf(sacc[r] * 0.0625f, 30.f));
    }

    // A-frags of P (reused across dt): lane m=l31, k=h*8+j (+16 for half 2)
    bfx8 pf0 = *(const bfx8*)&lp[w * 32 + l31][h * 8];
    bfx8 pf1 = *(const bfx8*)&lp[w * 32 + l31][16 + h * 8];
    dacc = MFMA32(pf0, onesf, dacc);
    dacc = MFMA32(pf1, onesf, dacc);
#pragma unroll
    for (int dt = 0; dt < 8; dt++) {
      bfx8 vf0 = *(const bfx8*)&lvt[cur][dt * 32 + l31][h * 8];
      bfx8 vf1 = *(const bfx8*)&lvt[cur][dt * 32 + l31][16 + h * 8];
      oacc[dt] = MFMA32(pf0, vf0, oacc[dt]);
      oacc[dt] = MFMA32(pf1, vf1, oacc[dt]);
    }
    __syncthreads();               // staged lk/lvt visible; lvt[cur] reads done
  }

  // epilogue: add self term, normalize, scatter into concat[b,m,hh*256+d]
#pragma unroll
  for (int r = 0; r < 16; r++) {
    int row = (r & 3) + 8 * (r >> 2) + 4 * h;   // 0..31
    float ps = __shfl(ps_l, row);               // lane 'row' holds this row's ps
    float dinv = 1.f / (dacc[r] + ps);
    const __bf16* mvrow = mv + mbase + (long)row * 256;
    __bf16* crow = concat + ((long)(b * 1024 + mw + row)) * 2048 + hh * 256;
#pragma unroll
    for (int dt = 0; dt < 8; dt++) {
      int d = dt * 32 + l31;
      crow[d] = (__bf16)((oacc[dt][r] + ps * (float)mvrow[d]) * dinv);
    }
  }
}

// ---------------- LayerNorm over 4 f32 partials + residual ----------------
__global__ __launch_bounds__(256)
void ln4_kernel(const float* __restrict__ parts, const float* __restrict__ res,
                const float* __restrict__ g, const float* __restrict__ beta,
                __bf16* __restrict__ outb, float* __restrict__ outf) {
  int row  = blockIdx.x * 4 + (threadIdx.x >> 6);
  int lane = threadIdx.x & 63;
  const float* p = parts + (long)row * 256 + lane * 4;
  f32x4 a0 = *(const f32x4*)p;
  f32x4 a1 = *(const f32x4*)(p + 1048576);
  f32x4 a2 = *(const f32x4*)(p + 2097152);
  f32x4 a3 = *(const f32x4*)(p + 3145728);
  f32x4 rv = *(const f32x4*)(res + (long)row * 256 + lane * 4);
  float v[4], s1 = 0.f, s2 = 0.f;
#pragma unroll
  for (int i = 0; i < 4; i++) {
    v[i] = a0[i] + a1[i] + a2[i] + a3[i] + rv[i];
    s1 += v[i];
    s2 += v[i] * v[i];
  }
#pragma unroll
  for (int off = 32; off >= 1; off >>= 1) {
    s1 += __shfl_xor(s1, off);
    s2 += __shfl_xor(s2, off);
  }
  float mean = s1 * (1.f / 256.f);
  float var  = fmaxf(s2 * (1.f / 256.f) - mean * mean, 0.f);
  float rstd = rsqrtf(var + 1e-6f);
#pragma unroll
  for (int i = 0; i < 4; i++) {
    int c = lane * 4 + i;
    float o = (v[i] - mean) * rstd * g[c] + beta[c];
    if (outb) outb[(long)row * 256 + c] = (__bf16)o;
    if (outf) outf[(long)row * 256 + c] = o;
  }
}

extern "C" void kernel_launch(void* const* d_in, const int* in_sizes, int n_in,
                              void* d_out, int out_size, void* d_ws, size_t ws_size,
                              hipStream_t stream) {
  const float* state  = (const float*)d_in[0];
  const float* input  = (const float*)d_in[1];
  const float* Wk     = (const float*)d_in[2];
  const float* bk     = (const float*)d_in[3];
  const float* Wv     = (const float*)d_in[4];
  const float* bv     = (const float*)d_in[5];
  const float* Wq     = (const float*)d_in[6];
  const float* bq     = (const float*)d_in[7];
  const float* Wo     = (const float*)d_in[8];
  const float* bo     = (const float*)d_in[9];
  const float* ln1g   = (const float*)d_in[10];
  const float* ln1b   = (const float*)d_in[11];
  const float* W_in   = (const float*)d_in[12];
  const float* b_in   = (const float*)d_in[13];
  const float* Wg_nl  = (const float*)d_in[14];
  const float* bg_nl  = (const float*)d_in[15];
  const float* Wg_l   = (const float*)d_in[16];
  const float* bg_l   = (const float*)d_in[17];
  const float* Wg_o   = (const float*)d_in[18];
  const float* bg_o   = (const float*)d_in[19];
  const float* ln2g   = (const float*)d_in[20];
  const float* ln2b   = (const float*)d_in[21];
  float* out = (float*)d_out;

  const size_t needed_elems = 28442624;   // 56.9 MB, proven budget
  if (ws_size < needed_elems * sizeof(__bf16)) return;

  __bf16* ws = (__bf16*)d_ws;
  size_t off = 0;
  auto alloc = [&](size_t n) { __bf16* p = ws + off; off += n; return p; };
  __bf16* Wkvqt  = alloc(655360);    // [2560][256]: Wk^T | Wv^T | Wq^T(8)
  __bf16* Wot    = alloc(524288);    // [256][2048]
  __bf16* ik     = alloc(4194304);   // [16384][256]
  __bf16* ivT    = alloc(4194304);   // [4][128][256][32]
  __bf16* mk     = alloc(1048576);   // [4096][256]
  __bf16* mv     = alloc(1048576);
  __bf16* qbuf   = alloc(8388608);   // [8][4096][256]
  __bf16* concat = alloc(8388608);   // [4096][2048]
  // FFN/late-phase aliases over dead buffers
  float*  wo_parts = (float*)qbuf;           // f32[4][4096][256] = 16MB (qbuf dead after attn)
  __bf16* x      = mv;                       // bf16 LN1 out (mv dead after attn)
  __bf16* hbuf   = ik;                       // [4096][1024]
  __bf16* t12    = qbuf;                     // [4096][2048] (wo_parts dead after LN1)
  float*  ff_parts = (float*)ik;             // f32[4][4096][256] = 16MB over ik+ivT (dead after FF2)
  __bf16* Wffn   = concat;                   // FFN weights^T (2621440 el)
  float*  xf     = (float*)(concat + 3670016); // f32 residual [4096][256]

  dim3 blk(256);

  trans_attn<<<dim3(4608), blk, 0, stream>>>(Wk, Wv, Wq, Wo, Wkvqt, Wot);

  // fused K|V input projection: N=512
  gemm_bt<<<dim3(128, 4), blk, 0, stream>>>(nullptr, input, Wkvqt, bk, bv, nullptr,
                                            ik, ivT, nullptr, nullptr,
                                            16384, 512, 256, 256, 1, 4, 0);
  // fused K|V|Q state projection: N=2560
  gemm_bt<<<dim3(32, 20), blk, 0, stream>>>(nullptr, state, Wkvqt, bk, bv, bq,
                                            mk, mv, qbuf, nullptr,
                                            4096, 2560, 256, 256, 1, 5, 0);

  attn_kernel<<<dim3(8, 4, 8), blk, 0, stream>>>(qbuf, ik, ivT, mk, mv, concat);

  // Wo: split-K (4 x 512) -> f32 partials, 256 blocks
  gemm_bt<<<dim3(32, 2, 4), blk, 0, stream>>>(concat, nullptr, Wot, bo, nullptr, nullptr,
                                              nullptr, nullptr, nullptr, wo_parts,
                                              4096, 256, 2048, 512, 0, 7, 0);
  ln4_kernel<<<dim3(1024), blk, 0, stream>>>(wo_parts, state, ln1g, ln1b, x, xf);

  trans_ffn<<<dim3(10240), blk, 0, stream>>>(W_in, Wg_nl, Wg_l, Wg_o, Wffn);

  gemm_bt<<<dim3(32, 8), blk, 0, stream>>>(x, nullptr, Wffn, b_in, nullptr, nullptr,
                                           hbuf, nullptr, nullptr, nullptr,
                                           4096, 1024, 256, 256, 0, 0, 1);
  // fused Wg_nl|Wg_l: N=2048, relu on first half
  gemm_bt<<<dim3(32, 16), blk, 0, stream>>>(hbuf, nullptr, Wffn + 262144, bg_nl, bg_l, nullptr,
                                            t12, nullptr, nullptr, nullptr,
                                            4096, 2048, 1024, 1024, 0, 6, 0);
  // Wg_o with gating fused into the stager: split-K (4 x 256) -> f32 partials
  gemm_bt<<<dim3(32, 2, 4), blk, 0, stream>>>(t12, nullptr, Wffn + 2359296, bg_o, nullptr, nullptr,
                                              nullptr, nullptr, nullptr, ff_parts,
                                              4096, 256, 1024, 256, 2, 7, 0);
  ln4_kernel<<<dim3(1024), blk, 0, stream>>>(ff_parts, xf, ln2g, ln2b, nullptr, out);
}